// Round 5
// baseline (2020.160 us; speedup 1.0000x reference)
//
#include <hip/hip_runtime.h>
#include <stdint.h>

#define D 4096

typedef __attribute__((ext_vector_type(8))) short bf16x8;
typedef __attribute__((ext_vector_type(4))) float f32x4;

__device__ __forceinline__ ushort f2bf(float f) {
    uint32_t u = __float_as_uint(f);
    uint32_t r = (u + 0x7FFFu + ((u >> 16) & 1u)) >> 16;
    return (ushort)r;
}
__device__ __forceinline__ float bf2f(ushort h) {
    return __uint_as_float(((uint32_t)h) << 16);
}
__device__ __forceinline__ float sgnf(float z) {
    return (z > 0.f) ? 1.f : ((z < 0.f) ? -1.f : 0.f);
}

// ---- GEMV mimicking OpenBLAS AVX2 sgemv_t bit-for-bit (f32) ----
// 8 lanes per output row; lane l accumulates k = l, l+8, l+16, ... ascending with fmaf
// (one ymm accumulator per row in OpenBLAS); then the exact vextract/vhadd reduction
// tree: b_l = a_l + a_{l+4};  s = (b0+b1) + (b2+b3).
__global__ __launch_bounds__(256) void gemv_blas8(const float* __restrict__ W,
                                                  const float* __restrict__ v,
                                                  const float* __restrict__ bias,
                                                  float* __restrict__ z,
                                                  float* __restrict__ act, int doAct) {
    int gid = blockIdx.x * 256 + threadIdx.x;
    int row = gid >> 3;        // 8 threads per row
    int l = gid & 7;           // SIMD lane within the emulated ymm
    const float* wr = W + (size_t)row * D;
    float acc = 0.f;
    for (int k = l; k < D; k += 8) acc = fmaf(wr[k], v[k], acc);
    // reduction tree: (lo+hi) then two vhaddps — via shfl_xor (IEEE add is commutative,
    // so lane0's value equals OpenBLAS's scalar result bit-for-bit)
    float b = acc + __shfl_xor(acc, 4);   // b_l = a_l + a_{l+4}
    float c = b + __shfl_xor(b, 1);       // c_0 = b0+b1, c_2 = b2+b3
    float s = c + __shfl_xor(c, 2);       // s = (b0+b1)+(b2+b3)
    if (l == 0) {
        z[row] = s;
        if (doAct) act[row] = fmaxf(s + bias[row], 0.f);
    }
}

// ------------- vector prep, pure f32 (bit-exact vs numpy given matching z) -------------
__global__ __launch_bounds__(256) void vecprep32(const float* __restrict__ z1,
                                                 const float* __restrict__ z2,
                                                 const float* __restrict__ z3,
                                                 const float* __restrict__ a1,
                                                 const float* __restrict__ a2,
                                                 const float* __restrict__ b3,
                                                 float* __restrict__ out,
                                                 float* __restrict__ s3,
                                                 float* __restrict__ g2,
                                                 float* __restrict__ g1) {
    int i = blockIdx.x * 256 + threadIdx.x;
    float z3v = z3[i];
    float o = z3v + b3[i];
    out[i] = o;
    s3[i] = o / (z3v + 1e-9f * sgnf(z3v));
    float z2v = z2[i];
    g2[i] = a2[i] / (z2v + 1e-9f * sgnf(z2v));
    float z1v = z1[i];
    g1[i] = a1[i] / (z1v + 1e-9f * sgnf(z1v));
}

// ------------- triple-split GEMM: O[i,c] = (Σ_k Asc[i,k]·B[k,c]) · cs[c] -------------
// SCALED=1: A-element = rs[i]·ks[k]·A[i,k]. 6 MFMA products (hh+hm+mh+mm+hl+lh),
// residual ~3·2^-24 — fp32-level; differences vs the ref's f32 sgemm are diffuse.
constexpr int BM = 128, BN = 128, BK = 32, LDK = 40;

template <int SCALED>
__global__ __launch_bounds__(256, 2) void gemm3(const float* __restrict__ A,
                                                const float* __restrict__ B,
                                                const float* __restrict__ rs,
                                                const float* __restrict__ ks,
                                                const float* __restrict__ cs,
                                                float* __restrict__ O) {
    __shared__ ushort Ahs[BM][LDK], Ams[BM][LDK], Als[BM][LDK];
    __shared__ ushort Bhs[BN][LDK], Bms[BN][LDK], Bls[BN][LDK];

    int t = threadIdx.x;
    int lane = t & 63, wv = t >> 6;
    int wr = wv >> 1, wc = wv & 1;
    int r = lane & 15, g = lane >> 4;
    size_t row0 = (size_t)blockIdx.y * BM;
    size_t col0 = (size_t)blockIdx.x * BN;

    int sArow = t >> 1;
    int sAk = (t & 1) * 16;
    int sBcol = t & 127;
    int sBk = (t >> 7) * 16;

    f32x4 acc[4][4];
#pragma unroll
    for (int m = 0; m < 4; m++)
#pragma unroll
        for (int n = 0; n < 4; n++) acc[m][n] = (f32x4){0.f, 0.f, 0.f, 0.f};

    float av[16], bv[16];

    auto LOADT = [&](int k0) {
        const float4* pa = (const float4*)(A + (row0 + sArow) * (size_t)D + k0 + sAk);
#pragma unroll
        for (int q = 0; q < 4; q++) {
            float4 w = pa[q];
            av[q * 4 + 0] = w.x; av[q * 4 + 1] = w.y; av[q * 4 + 2] = w.z; av[q * 4 + 3] = w.w;
        }
        if (SCALED) {
            float rsv = rs[row0 + sArow];
            const float4* pk = (const float4*)(ks + k0 + sAk);
#pragma unroll
            for (int q = 0; q < 4; q++) {
                float4 kk = pk[q];
                av[q * 4 + 0] *= rsv * kk.x; av[q * 4 + 1] *= rsv * kk.y;
                av[q * 4 + 2] *= rsv * kk.z; av[q * 4 + 3] *= rsv * kk.w;
            }
        }
        const float* pb = B + ((size_t)k0 + sBk) * D + col0 + sBcol;
#pragma unroll
        for (int kk = 0; kk < 16; kk++) bv[kk] = pb[(size_t)kk * D];
    };

    auto pack8 = [](const ushort* s) {
        uint4 u;
        u.x = (uint)s[0] | ((uint)s[1] << 16);
        u.y = (uint)s[2] | ((uint)s[3] << 16);
        u.z = (uint)s[4] | ((uint)s[5] << 16);
        u.w = (uint)s[6] | ((uint)s[7] << 16);
        return u;
    };

    LOADT(0);

    for (int kt = 0; kt < D / BK; ++kt) {
        __syncthreads();
        {
            ushort h[16], m_[16], l[16];
#pragma unroll
            for (int j = 0; j < 16; j++) {
                float v = av[j];
                ushort hh = f2bf(v);
                float r1 = v - bf2f(hh);
                ushort mm = f2bf(r1);
                ushort ll = f2bf(r1 - bf2f(mm));
                h[j] = hh; m_[j] = mm; l[j] = ll;
            }
            *(uint4*)&Ahs[sArow][sAk] = pack8(h);
            *(uint4*)&Ahs[sArow][sAk + 8] = pack8(h + 8);
            *(uint4*)&Ams[sArow][sAk] = pack8(m_);
            *(uint4*)&Ams[sArow][sAk + 8] = pack8(m_ + 8);
            *(uint4*)&Als[sArow][sAk] = pack8(l);
            *(uint4*)&Als[sArow][sAk + 8] = pack8(l + 8);
        }
        {
            ushort h[16], m_[16], l[16];
#pragma unroll
            for (int j = 0; j < 16; j++) {
                float v = bv[j];
                ushort hh = f2bf(v);
                float r1 = v - bf2f(hh);
                ushort mm = f2bf(r1);
                ushort ll = f2bf(r1 - bf2f(mm));
                h[j] = hh; m_[j] = mm; l[j] = ll;
            }
            *(uint4*)&Bhs[sBcol][sBk] = pack8(h);
            *(uint4*)&Bhs[sBcol][sBk + 8] = pack8(h + 8);
            *(uint4*)&Bms[sBcol][sBk] = pack8(m_);
            *(uint4*)&Bms[sBcol][sBk + 8] = pack8(m_ + 8);
            *(uint4*)&Bls[sBcol][sBk] = pack8(l);
            *(uint4*)&Bls[sBcol][sBk + 8] = pack8(l + 8);
        }
        __syncthreads();
        if (kt + 1 < D / BK) LOADT((kt + 1) * BK);

        bf16x8 bh[4], bm[4], bl[4];
#pragma unroll
        for (int n = 0; n < 4; n++) {
            bh[n] = *(const bf16x8*)&Bhs[wc * 64 + n * 16 + r][g * 8];
            bm[n] = *(const bf16x8*)&Bms[wc * 64 + n * 16 + r][g * 8];
            bl[n] = *(const bf16x8*)&Bls[wc * 64 + n * 16 + r][g * 8];
        }
#pragma unroll
        for (int m = 0; m < 4; m++) {
            bf16x8 ah = *(const bf16x8*)&Ahs[wr * 64 + m * 16 + r][g * 8];
            bf16x8 am = *(const bf16x8*)&Ams[wr * 64 + m * 16 + r][g * 8];
            bf16x8 al = *(const bf16x8*)&Als[wr * 64 + m * 16 + r][g * 8];
#pragma unroll
            for (int n = 0; n < 4; n++) {
                acc[m][n] = __builtin_amdgcn_mfma_f32_16x16x32_bf16(ah, bh[n], acc[m][n], 0, 0, 0);
                acc[m][n] = __builtin_amdgcn_mfma_f32_16x16x32_bf16(ah, bm[n], acc[m][n], 0, 0, 0);
                acc[m][n] = __builtin_amdgcn_mfma_f32_16x16x32_bf16(am, bh[n], acc[m][n], 0, 0, 0);
                acc[m][n] = __builtin_amdgcn_mfma_f32_16x16x32_bf16(am, bm[n], acc[m][n], 0, 0, 0);
                acc[m][n] = __builtin_amdgcn_mfma_f32_16x16x32_bf16(ah, bl[n], acc[m][n], 0, 0, 0);
                acc[m][n] = __builtin_amdgcn_mfma_f32_16x16x32_bf16(al, bh[n], acc[m][n], 0, 0, 0);
            }
        }
    }

    float csv[4];
#pragma unroll
    for (int n = 0; n < 4; n++) csv[n] = cs[col0 + wc * 64 + n * 16 + r];
#pragma unroll
    for (int m = 0; m < 4; m++)
#pragma unroll
        for (int n = 0; n < 4; n++) {
#pragma unroll
            for (int j = 0; j < 4; j++) {
                size_t grow = row0 + wr * 64 + m * 16 + g * 4 + j;
                size_t gcol = col0 + wc * 64 + n * 16 + r;
                O[grow * D + gcol] = acc[m][n][j] * csv[n];
            }
        }
}

extern "C" void kernel_launch(void* const* d_in, const int* in_sizes, int n_in,
                              void* d_out, int out_size, void* d_ws, size_t ws_size,
                              hipStream_t stream) {
    const float* x = (const float*)d_in[0];
    const float* W1 = (const float*)d_in[1];
    const float* b1 = (const float*)d_in[2];
    const float* W2 = (const float*)d_in[3];
    const float* b2 = (const float*)d_in[4];
    const float* W3 = (const float*)d_in[5];
    const float* b3 = (const float*)d_in[6];

    float* out = (float*)d_out;  // first D floats
    float* Rout = out + D;       // D*D floats

    char* ws = (char*)d_ws;
    float* z1 = (float*)ws;
    float* z2 = z1 + D;
    float* z3 = z2 + D;
    float* a1 = z3 + D;
    float* a2 = a1 + D;
    float* s3 = a2 + D;
    float* g2 = s3 + D;
    float* g1 = g2 + D;
    size_t smallB = (size_t)D * 8 * sizeof(float);
    float* C = (float*)(ws + smallB);  // D*D fp32 intermediate (64 MB)

    // forward pass — bit-exact emulation of numpy-f32 (OpenBLAS AVX2 sgemv_t)
    gemv_blas8<<<(D * 8) / 256, 256, 0, stream>>>(W1, x, b1, z1, a1, 1);
    gemv_blas8<<<(D * 8) / 256, 256, 0, stream>>>(W2, a1, b2, z2, a2, 1);
    gemv_blas8<<<(D * 8) / 256, 256, 0, stream>>>(W3, a2, b3, z3, nullptr, 0);
    vecprep32<<<D / 256, 256, 0, stream>>>(z1, z2, z3, a1, a2, b3, out, s3, g2, g1);

    // LRP backward: C = (s3·W3·g2) @ W2 · g1 ; R = C @ W1 · x
    dim3 gg(D / BN, D / BM);
    gemm3<1><<<gg, 256, 0, stream>>>(W3, W2, s3, g2, g1, C);
    gemm3<0><<<gg, 256, 0, stream>>>(C, W1, nullptr, nullptr, x, Rout);
}